// Round 4
// baseline (1308.957 us; speedup 1.0000x reference)
//
#include <hip/hip_runtime.h>
#include <math.h>

#define B_ 32
#define S_ 256
#define H_ 2048
#define NH_ 16
#define HD_ 128
#define M_ (B_*S_)
#define K_ H_

typedef unsigned short u16;
typedef unsigned int   u32;
typedef __attribute__((ext_vector_type(8))) short  short8;   // 8 bf16 (4 VGPRs) MFMA A/B frag
typedef __attribute__((ext_vector_type(8))) unsigned short ushort8;
typedef __attribute__((ext_vector_type(4))) float  floatx4;  // MFMA C/D frag

typedef __attribute__((address_space(3))) u32 lds_u32;
typedef __attribute__((address_space(1))) const u32 glb_u32;

__device__ __forceinline__ u16 rne_bf16(float f) {
    u32 u = __float_as_uint(f);
    return (u16)((u + 0x7fffu + ((u >> 16) & 1u)) >> 16);
}
__device__ __forceinline__ float bf16_to_f(u16 h) {
    return __uint_as_float(((u32)h) << 16);
}
// async 16B global->LDS; lds addr must be wave-uniform base (+ lane*16 implicit)
__device__ __forceinline__ void gll16(const u16* g, u16* l) {
    __builtin_amdgcn_global_load_lds((glb_u32*)g, (lds_u32*)l, 16, 0, 0);
}

// ---------------------------------------------------------------------------
// fp32 -> (hi, lo) bf16 split.  x = hi + lo + O(2^-17 |x|)
// ---------------------------------------------------------------------------
__global__ __launch_bounds__(256) void split_kernel(const float* __restrict__ x,
    u16* __restrict__ hi, u16* __restrict__ lo, int n4)
{
    int i = blockIdx.x * 256 + threadIdx.x;
    if (i >= n4) return;
    float4 v = ((const float4*)x)[i];
    float vv[4] = {v.x, v.y, v.z, v.w};
    u16 h[4], l[4];
#pragma unroll
    for (int j = 0; j < 4; ++j) {
        h[j] = rne_bf16(vv[j]);
        l[j] = rne_bf16(vv[j] - bf16_to_f(h[j]));
    }
    ((ushort4*)hi)[i] = make_ushort4(h[0], h[1], h[2], h[3]);
    ((ushort4*)lo)[i] = make_ushort4(l[0], l[1], l[2], l[3]);
}

// ---------------------------------------------------------------------------
// C = A @ B^T via 3-pass split-bf16 MFMA (hi*hi + hi*lo + lo*hi), fp32 acc.
// 128x128 tile, BK=32, 256 thr = 4 waves (2Mx2N), wave tile 64x64.
// KEY CHANGE vs r2/r3: LDS cut to 64 KiB (4 streams x 2 buffers x 8 KiB) so
// TWO independent blocks are resident per CU.  Round-3 ablation showed all
// intra-step schedules tie at 1 block/CU (burst-aligned waves: LDS-read bursts
// and MFMA bursts alternate, never overlap).  Two unaligned blocks give burst
// complementarity + cover the per-step rendezvous; the retained depth-2
// counted-vmcnt pipeline (tile t+2 staged mid-step, vmcnt(8) at step end,
// never drain-0) keeps each block free of exposed staging latency.
// LDS plane-major: chunk (row,kc) at slot kc*128+row -> conflict-free b128
// frag reads + gll16-linear staging.
// T1: bijective XCD swizzle (grid 1024 = 8 XCD x 128; XCD k owns by 8k..8k+7).
// mode 0: write bf16 head-major [B,NH,S,HD] (bx == head).  mode 1: fp32 [M,2048].
// ---------------------------------------------------------------------------
__global__ __launch_bounds__(256, 2) void gemm_split128(
    const u16* __restrict__ Ahi, const u16* __restrict__ Alo,
    const u16* __restrict__ Bhi, const u16* __restrict__ Blo,
    void* __restrict__ outv, int mode)
{
    __shared__ u16 sAhi[2][4096], sAlo[2][4096], sBhi[2][4096], sBlo[2][4096];

    const int tid  = threadIdx.x;
    const int lane = tid & 63, w = tid >> 6;
    const int wm   = w >> 1, wn = w & 1;            // wave grid 2 (M) x 2 (N)
    const int r15  = lane & 15, quad = lane >> 4;

    // T1: bijective XCD swizzle. nwg=1024, 8 XCDs, q=128.
    const int bid = blockIdx.x;
    const int swz = (bid & 7) * 128 + (bid >> 3);
    const int bx  = swz & 15;                        // N-tile 0..15 (== head)
    const int by  = swz >> 4;                        // M-tile 0..63

    // staging map: slot = (w*2+rep)*64 + lane; kc = slot>>7, row = slot&127
    const u16* srcs[4]  = {Ahi, Alo, Bhi, Blo};
    const int  tile0[4] = {by*128, by*128, bx*128, bx*128};
    const u16* gp[2][4];
    int ldsoff[2];
#pragma unroll
    for (int rep = 0; rep < 2; ++rep) {
        int slot = (w*2 + rep)*64 + lane;
        int kc = slot >> 7, row = slot & 127;
#pragma unroll
        for (int b = 0; b < 4; ++b)
            gp[rep][b] = srcs[b] + (size_t)(tile0[b] + row) * K_ + kc*8;
        ldsoff[rep] = (w*2 + rep)*512;               // wave-uniform u16 offset
    }

    // fragment read bases (u16 index): chunk (row,kc) at slot kc*128+row
    const int aBase = (quad*128 + wm*64 + r15) * 8;
    const int bBase = (quad*128 + wn*64 + r15) * 8;

    const floatx4 fzero = {0.f, 0.f, 0.f, 0.f};
    floatx4 acc[4][4];
#pragma unroll
    for (int mi = 0; mi < 4; ++mi)
#pragma unroll
        for (int ni = 0; ni < 4; ++ni) acc[mi][ni] = fzero;

#define STAGE8(nbuf) do {                                                       \
        gll16(gp[0][0], &sAhi[nbuf][ldsoff[0]]); gll16(gp[1][0], &sAhi[nbuf][ldsoff[1]]); \
        gll16(gp[0][1], &sAlo[nbuf][ldsoff[0]]); gll16(gp[1][1], &sAlo[nbuf][ldsoff[1]]); \
        gll16(gp[0][2], &sBhi[nbuf][ldsoff[0]]); gll16(gp[1][2], &sBhi[nbuf][ldsoff[1]]); \
        gll16(gp[0][3], &sBlo[nbuf][ldsoff[0]]); gll16(gp[1][3], &sBlo[nbuf][ldsoff[1]]); \
        gp[0][0] += 32; gp[1][0] += 32; gp[0][1] += 32; gp[1][1] += 32;          \
        gp[0][2] += 32; gp[1][2] += 32; gp[0][3] += 32; gp[1][3] += 32; } while (0)

#define MFMA3(dst, ahh, all, bhh, bll)                                          \
        dst = __builtin_amdgcn_mfma_f32_16x16x32_bf16(ahh, bhh, dst, 0, 0, 0);  \
        dst = __builtin_amdgcn_mfma_f32_16x16x32_bf16(ahh, bll, dst, 0, 0, 0);  \
        dst = __builtin_amdgcn_mfma_f32_16x16x32_bf16(all, bhh, dst, 0, 0, 0);

    // prologue: stage tiles 0 and 1; wait only for tile 0 (8 oldest of 16)
    STAGE8(0);
    STAGE8(1);
    asm volatile("s_waitcnt vmcnt(8)" ::: "memory");
    __builtin_amdgcn_s_barrier();

    const int NT = K_/32;
    int cur = 0;
    for (int kt = 0; kt < NT; ++kt) {
        // all 16 frag reads up front; compiler interleaves lgkm waits into MFMAs
        short8 ah[4], al[4], bh[4], bl[4];
#pragma unroll
        for (int mi = 0; mi < 4; ++mi) {
            ah[mi] = *(const short8*)&sAhi[cur][aBase + mi*128];
            al[mi] = *(const short8*)&sAlo[cur][aBase + mi*128];
        }
#pragma unroll
        for (int ni = 0; ni < 4; ++ni) {
            bh[ni] = *(const short8*)&sBhi[cur][bBase + ni*128];
            bl[ni] = *(const short8*)&sBlo[cur][bBase + ni*128];
        }
        __builtin_amdgcn_s_setprio(1);
#pragma unroll
        for (int mi = 0; mi < 2; ++mi)
#pragma unroll
            for (int ni = 0; ni < 4; ++ni) { MFMA3(acc[mi][ni], ah[mi], al[mi], bh[ni], bl[ni]); }
        __builtin_amdgcn_s_setprio(0);

        // all reads of buf[cur] complete in every wave -> safe to restage it
        asm volatile("s_waitcnt lgkmcnt(0)" ::: "memory");
        __builtin_amdgcn_s_barrier();
        if (kt < NT - 2) {
            STAGE8(cur);                       // tile kt+2 into the just-freed buffer
            __builtin_amdgcn_sched_barrier(0); // keep issue point ahead of MFMA tail
        }

        __builtin_amdgcn_s_setprio(1);
#pragma unroll
        for (int mi = 2; mi < 4; ++mi)
#pragma unroll
            for (int ni = 0; ni < 4; ++ni) { MFMA3(acc[mi][ni], ah[mi], al[mi], bh[ni], bl[ni]); }
        __builtin_amdgcn_s_setprio(0);

        // counted wait: oldest 8 = tile kt+1 (next buffer); tile kt+2 stays in flight
        if (kt < NT - 2)       asm volatile("s_waitcnt vmcnt(8)" ::: "memory");
        else if (kt == NT - 2) asm volatile("s_waitcnt vmcnt(0)" ::: "memory");
        if (kt < NT - 1) __builtin_amdgcn_s_barrier();
        cur ^= 1;
    }
#undef STAGE8
#undef MFMA3

    // C/D layout: col = lane&15, row = quad*4 + reg  [m89/m91 verified]
    if (mode == 0) {
        u16* out = (u16*)outv;                       // [B, NH, S, HD], head == bx
#pragma unroll
        for (int mi = 0; mi < 4; ++mi)
#pragma unroll
            for (int r = 0; r < 4; ++r) {
                int m  = by*128 + wm*64 + mi*16 + quad*4 + r;
                int bb = m >> 8, ss = m & 255;
                size_t base = (((size_t)(bb*NH_ + bx)) * S_ + ss) * HD_ + wn*64 + r15;
#pragma unroll
                for (int ni = 0; ni < 4; ++ni)
                    out[base + ni*16] = rne_bf16(acc[mi][ni][r]);
            }
    } else {
        float* out = (float*)outv;                   // [M, 2048]
#pragma unroll
        for (int mi = 0; mi < 4; ++mi)
#pragma unroll
            for (int r = 0; r < 4; ++r) {
                int m = by*128 + wm*64 + mi*16 + quad*4 + r;
                size_t base = (size_t)m * H_ + bx*128 + wn*64 + r15;
#pragma unroll
                for (int ni = 0; ni < 4; ++ni)
                    out[base + ni*16] = acc[mi][ni][r];
            }
    }
}

// ---------------------------------------------------------------------------
// RoPE in-place on bf16 q,k in [B,NH,S,HD]; pair (i, i+64). Accurate cosf/sinf.
// ---------------------------------------------------------------------------
__global__ __launch_bounds__(256) void rope_bf(u16* __restrict__ q, u16* __restrict__ k)
{
    int idx = blockIdx.x * 256 + threadIdx.x;       // pair index
    u16* p = blockIdx.y ? k : q;
    int i  = idx & 63;
    int s  = (idx >> 6) & (S_ - 1);
    int bh = idx >> 14;
    size_t base = ((size_t)bh * S_ + s) * HD_;
    float f = expf((float)i * -0.14391156831212788f);   // 10000^(-i/64)
    float ang = (float)s * f;
    float c = cosf(ang), sn = sinf(ang);
    float x0 = bf16_to_f(p[base + i]), x1 = bf16_to_f(p[base + i + 64]);
    p[base + i]      = rne_bf16(x0 * c - x1 * sn);
    p[base + i + 64] = rne_bf16(x1 * c + x0 * sn);
}

// ---------------------------------------------------------------------------
// Attention, bf16 MFMA. Block = 256 thr (4 waves) handles (b,h) x 64 q-rows.
// Scores kept in C-layout registers (wave w owns q-rows w*16..+15, all 256 cols);
// softmax via 16-lane shuffle; P -> LDS (plane-major) -> A-operand for PV.
// LDS 48KB: shQK = Qs(16K)+Ks(16K) reused as Pb(32K); shV = Vt transposed (16K).
// Output written as hi/lo split bf16 [M, 2048] for the final split GEMM.
// ---------------------------------------------------------------------------
#define SCALE 0.08838834764831845f

__global__ __launch_bounds__(256) void attn_mfma(
    const u16* __restrict__ Q, const u16* __restrict__ K, const u16* __restrict__ V,
    u16* __restrict__ Ohi, u16* __restrict__ Olo)
{
    __shared__ u16 shQK[16384];
    __shared__ u16 shV[8192];
    u16* Qs = shQK;            // planes [16][64] chunks of 8 bf16
    u16* Ks = shQK + 8192;     // planes [16][64]
    u16* Pb = shQK;            // planes [32][64]  (after Qs/Ks dead)

    const int tid = threadIdx.x;
    const int lane = tid & 63, w = tid >> 6;
    const int r15 = lane & 15, quad = lane >> 4;
    const int bh = blockIdx.x;
    const int q0 = blockIdx.y << 6;
    const int wq = w * 16;

    const u16* Qg = Q + ((size_t)bh * S_ + q0) * HD_;
    const u16* Kg = K + (size_t)bh * S_ * HD_;
    const u16* Vg = V + (size_t)bh * S_ * HD_;

    // stage Q tile 64x128 -> plane-major
#pragma unroll
    for (int p = 0; p < 4; ++p) {
        int task = tid + (p << 8);
        int r = task & 63, c = task >> 6;
        *(uint4*)&Qs[(c*64 + r)*8] = *(const uint4*)&Qg[(size_t)r*HD_ + c*8];
    }

    const floatx4 fzero = {0.f, 0.f, 0.f, 0.f};
    floatx4 sc[4][4];                          // [kt][ni]; rows wq+quad*4+reg
    for (int kt = 0; kt < 4; ++kt) {
        __syncthreads();
#pragma unroll
        for (int p = 0; p < 4; ++p) {
            int task = tid + (p << 8);
            int r = task & 63, c = task >> 6;
            *(uint4*)&Ks[(c*64 + r)*8] = *(const uint4*)&Kg[(size_t)(kt*64 + r)*HD_ + c*8];
        }
        __syncthreads();
#pragma unroll
        for (int ni = 0; ni < 4; ++ni) sc[kt][ni] = fzero;
#pragma unroll
        for (int ks = 0; ks < 4; ++ks) {
            short8 a = *(const short8*)&Qs[((ks*4 + quad)*64 + wq + r15)*8];
#pragma unroll
            for (int ni = 0; ni < 4; ++ni) {
                short8 b = *(const short8*)&Ks[((ks*4 + quad)*64 + ni*16 + r15)*8];
                sc[kt][ni] = __builtin_amdgcn_mfma_f32_16x16x32_bf16(a, b, sc[kt][ni], 0, 0, 0);
            }
        }
    }
    __syncthreads();   // all Qs/Ks reads complete before Pb overwrites them

    // ---- softmax in registers (rows wq+quad*4+r; 16 col-lanes via shuffle) ----
#pragma unroll
    for (int kt = 0; kt < 4; ++kt)
#pragma unroll
        for (int ni = 0; ni < 4; ++ni) sc[kt][ni] *= SCALE;

    float rinv4[4], mrow4[4];
#pragma unroll
    for (int r = 0; r < 4; ++r) {
        float m = -1e30f;
#pragma unroll
        for (int kt = 0; kt < 4; ++kt)
#pragma unroll
            for (int ni = 0; ni < 4; ++ni) m = fmaxf(m, sc[kt][ni][r]);
#pragma unroll
        for (int o = 1; o < 16; o <<= 1) m = fmaxf(m, __shfl_xor(m, o));
        mrow4[r] = m;
    }
#pragma unroll
    for (int r = 0; r < 4; ++r) {
        float ssum = 0.f;
#pragma unroll
        for (int kt = 0; kt < 4; ++kt)
#pragma unroll
            for (int ni = 0; ni < 4; ++ni) {
                float e = __expf(sc[kt][ni][r] - mrow4[r]);
                sc[kt][ni][r] = e;
                ssum += e;
            }
#pragma unroll
        for (int o = 1; o < 16; o <<= 1) ssum += __shfl_xor(ssum, o);
        rinv4[r] = 1.f / ssum;
    }
    // write P bf16 -> Pb plane-major: elem(row,col) at chunk (col>>3)*64+row
#pragma unroll
    for (int r = 0; r < 4; ++r) {
        int row = wq + quad*4 + r;
#pragma unroll
        for (int kt = 0; kt < 4; ++kt)
#pragma unroll
            for (int ni = 0; ni < 4; ++ni) {
                int col = kt*64 + ni*16 + r15;
                Pb[((col >> 3)*64 + row)*8 + (col & 7)] = rne_bf16(sc[kt][ni][r] * rinv4[r]);
            }
    }

    // ---- O = P V ----
    floatx4 oacc[8];
#pragma unroll
    for (int di = 0; di < 8; ++di) oacc[di] = fzero;

    for (int vt = 0; vt < 4; ++vt) {
        __syncthreads();
        // stage V tile transposed: Vt planes [8][128] chunks; elem(d,s') at chunk (s'>>3)*128+d
#pragma unroll
        for (int p = 0; p < 4; ++p) {
            int task = tid + (p << 8);
            int r = task & 63, dc = task >> 6;          // s' = r, d-chunk dc
            ushort8 v = *(const ushort8*)&Vg[(size_t)(vt*64 + r)*HD_ + dc*8];
#pragma unroll
            for (int j = 0; j < 8; ++j)
                shV[(((r >> 3)*128) + dc*8 + j)*8 + (r & 7)] = v[j];
        }
        __syncthreads();
#pragma unroll
        for (int ks = 0; ks < 2; ++ks) {
            int colbase = vt*64 + ks*32 + quad*8;
            short8 a = *(const short8*)&Pb[((colbase >> 3)*64 + wq + r15)*8];
            int sp = ks*32 + quad*8;
#pragma unroll
            for (int di = 0; di < 8; ++di) {
                short8 b = *(const short8*)&shV[((sp >> 3)*128 + di*16 + r15)*8];
                oacc[di] = __builtin_amdgcn_mfma_f32_16x16x32_bf16(a, b, oacc[di], 0, 0, 0);
            }
        }
    }

    // epilogue: att[m][n] -> hi/lo split bf16, m = b*256+s, n = h*128 + d
    const int brow = bh >> 4, h = bh & 15;
#pragma unroll
    for (int r = 0; r < 4; ++r) {
        size_t base = ((size_t)(brow*S_ + q0 + wq + quad*4 + r)) * H_ + h*128 + r15;
#pragma unroll
        for (int di = 0; di < 8; ++di) {
            float x = oacc[di][r];
            u16 hb = rne_bf16(x);
            Ohi[base + di*16] = hb;
            Olo[base + di*16] = rne_bf16(x - bf16_to_f(hb));
        }
    }
}

// ---------------------------------------------------------------------------
extern "C" void kernel_launch(void* const* d_in, const int* in_sizes, int n_in,
                              void* d_out, int out_size, void* d_ws, size_t ws_size,
                              hipStream_t stream)
{
    const float* X  = (const float*)d_in[0];
    const float* Wp[4] = {(const float*)d_in[1], (const float*)d_in[2],
                          (const float*)d_in[3], (const float*)d_in[4]};   // q,k,v,o
    float* outp = (float*)d_out;

    char* ws = (char*)d_ws;
    u16* Xhi = (u16*)ws;                          //  33.5 MB
    u16* Xlo = (u16*)(ws + 33554432);             //  33.5 MB
    u16* Wsp = (u16*)(ws + 67108864);             //  8 x 8.4 MB (hi/lo per W)
    u16* Qbf = (u16*)(ws + 134217728);            //  33.5 MB [B,NH,S,HD]
    u16* Kbf = (u16*)(ws + 167772160);
    u16* Vbf = (u16*)(ws + 201326592);            //  total 235 MB
    u16* Ahi = Xhi;                               // alias: X-split dead after projections
    u16* Alo = Xlo;

    split_kernel<<<(M_*H_/4)/256, 256, 0, stream>>>(X, Xhi, Xlo, M_*H_/4);
    for (int i = 0; i < 4; ++i)
        split_kernel<<<(H_*H_/4)/256, 256, 0, stream>>>(Wp[i],
            Wsp + (size_t)(2*i)*4194304, Wsp + (size_t)(2*i+1)*4194304, H_*H_/4);

    gemm_split128<<<1024, 256, 0, stream>>>(Xhi, Xlo, Wsp + 0*4194304, Wsp + 1*4194304, Qbf, 0);
    gemm_split128<<<1024, 256, 0, stream>>>(Xhi, Xlo, Wsp + 2*4194304, Wsp + 3*4194304, Kbf, 0);
    gemm_split128<<<1024, 256, 0, stream>>>(Xhi, Xlo, Wsp + 4*4194304, Wsp + 5*4194304, Vbf, 0);
    rope_bf<<<dim3(32768, 2), 256, 0, stream>>>(Qbf, Kbf);
    attn_mfma<<<dim3(B_*NH_, 4), 256, 0, stream>>>(Qbf, Kbf, Vbf, Ahi, Alo);
    gemm_split128<<<1024, 256, 0, stream>>>(Ahi, Alo, Wsp + 6*4194304, Wsp + 7*4194304, outp, 1);
}

// Round 5
// 728.686 us; speedup vs baseline: 1.7963x; 1.7963x over previous
//
#include <hip/hip_runtime.h>
#include <math.h>

#define B_ 32
#define S_ 256
#define H_ 2048
#define NH_ 16
#define HD_ 128
#define M_ (B_*S_)
#define K_ H_

typedef unsigned short u16;
typedef unsigned int   u32;
typedef _Float16 half8 __attribute__((ext_vector_type(8)));   // 8 fp16 (4 VGPRs) MFMA A/B frag
typedef __attribute__((ext_vector_type(8))) unsigned short ushort8;
typedef __attribute__((ext_vector_type(4))) float  floatx4;   // MFMA C/D frag

typedef __attribute__((address_space(3))) u32 lds_u32;
typedef __attribute__((address_space(1))) const u32 glb_u32;

__device__ __forceinline__ u16 f2h(float f) {
    _Float16 h = (_Float16)f;          // v_cvt_f16_f32, RNE
    u16 r; __builtin_memcpy(&r, &h, 2); return r;
}
__device__ __forceinline__ float h2f(u16 u) {
    _Float16 h; __builtin_memcpy(&h, &u, 2); return (float)h;
}
// async 16B global->LDS; lds addr must be wave-uniform base (+ lane*16 implicit)
__device__ __forceinline__ void gll16(const u16* g, u16* l) {
    __builtin_amdgcn_global_load_lds((glb_u32*)g, (lds_u32*)l, 16, 0, 0);
}

// ---------------------------------------------------------------------------
// fp32 -> fp16 (RNE).  Precision note: the whole 16-bit domain is fp16 now;
// single-pass fp16 GEMM (rel err ~2^-12*sqrt(K) random-walk ~ 3e-4) is MORE
// accurate than the old bf16 intermediates (2^-9) that dominated the error.
// ---------------------------------------------------------------------------
__global__ __launch_bounds__(256) void cvt16(const float* __restrict__ x,
    u16* __restrict__ o, int n4)
{
    int i = blockIdx.x * 256 + threadIdx.x;
    if (i >= n4) return;
    float4 v = ((const float4*)x)[i];
    ((ushort4*)o)[i] = make_ushort4(f2h(v.x), f2h(v.y), f2h(v.z), f2h(v.w));
}

// ---------------------------------------------------------------------------
// C = A @ B^T, single-pass fp16 MFMA, fp32 acc.
// 256x256 tile, BK=32, 512 thr = 8 waves (2Mx4N), wave tile 128x64.
// Depth-2 counted-vmcnt pipeline (round-2 verified schedule): prologue stages
// tiles 0,1; step t restages buf[cur] with tile t+2 after lgkm(0)+barrier;
// step-end waits vmcnt(4) (= tile t+1 landed, t+2 in flight). Never drains to
// 0 in the main loop. 2 barriers/step.
// LDS 64 KiB: 2 streams x 2 buffers x 16 KiB, plane-major chunks (row,kc) at
// slot kc*256+row -> conflict-free b128 frag reads + gll16-linear staging.
// T1: bijective XCD swizzle (grid 256 = 8 XCD x 32).
// mode 0: write fp16 head-major [B,NH,S,HD].  mode 1: fp32 [M,2048].
// ---------------------------------------------------------------------------
__global__ __launch_bounds__(512, 2) void gemm_f16(
    const u16* __restrict__ A, const u16* __restrict__ Bm,
    void* __restrict__ outv, int mode)
{
    __shared__ u16 sA[2][8192], sB[2][8192];

    const int tid  = threadIdx.x;
    const int lane = tid & 63, w = tid >> 6;
    const int wm   = w >> 2, wn = w & 3;            // wave grid 2 (M) x 4 (N)
    const int r15  = lane & 15, quad = lane >> 4;

    // T1: XCD-aware bijective swizzle. 256 wgs, 8 XCDs
    const int bid = blockIdx.x;
    const int swz = (bid & 7) * 32 + (bid >> 3);
    const int bx  = swz & 7;                         // N-tile 0..7
    const int by  = swz >> 3;                        // M-tile 0..31

    // staging: thread -> (row = tid&255, chunks c0 and c0+2), c0 = tid>>8
    const int srow = tid & 255;
    const int c0   = tid >> 8;
    const u16* gA = A  + (size_t)(by*256 + srow) * K_ + c0*8;
    const u16* gB = Bm + (size_t)(bx*256 + srow) * K_ + c0*8;
    // per-wave LDS segments (u16 units): even half = chunk w*64+l, odd = +512 chunks
    const int segE = w * 512;
    const int segO = 4096 + w * 512;

    // fragment read bases (u16 index): chunk (row,kc) at slot kc*256+row
    const int aBase = (quad*256 + wm*128 + r15) * 8;
    const int bBase = (quad*256 + wn*64  + r15) * 8;

    const floatx4 fzero = {0.f, 0.f, 0.f, 0.f};
    floatx4 acc[8][4];
#pragma unroll
    for (int mi = 0; mi < 8; ++mi)
#pragma unroll
        for (int ni = 0; ni < 4; ++ni) acc[mi][ni] = fzero;

#define STAGE4(nbuf) do {                                                   \
        gll16(gA,      &sA[nbuf][segE]); gll16(gA + 16, &sA[nbuf][segO]);   \
        gll16(gB,      &sB[nbuf][segE]); gll16(gB + 16, &sB[nbuf][segO]);   \
        gA += 32; gB += 32; } while (0)

    // prologue: stage tiles 0 and 1; wait only for tile 0 (4 oldest of 8)
    STAGE4(0);
    STAGE4(1);
    asm volatile("s_waitcnt vmcnt(4)" ::: "memory");
    __builtin_amdgcn_s_barrier();

    const int NT = K_/32;
    int cur = 0;
    for (int kt = 0; kt < NT; ++kt) {
        // all 12 frag reads up front; compiler interleaves lgkm waits into MFMAs
        half8 a[8], b[4];
#pragma unroll
        for (int mi = 0; mi < 8; ++mi)
            a[mi] = *(const half8*)&sA[cur][aBase + mi*128];
#pragma unroll
        for (int ni = 0; ni < 4; ++ni)
            b[ni] = *(const half8*)&sB[cur][bBase + ni*128];

        __builtin_amdgcn_s_setprio(1);
#pragma unroll
        for (int mi = 0; mi < 4; ++mi)
#pragma unroll
            for (int ni = 0; ni < 4; ++ni)
                acc[mi][ni] = __builtin_amdgcn_mfma_f32_16x16x32_f16(a[mi], b[ni], acc[mi][ni], 0, 0, 0);
        __builtin_amdgcn_s_setprio(0);

        // all reads of buf[cur] complete in every wave -> safe to restage it
        asm volatile("s_waitcnt lgkmcnt(0)" ::: "memory");
        __builtin_amdgcn_sched_barrier(0);
        __builtin_amdgcn_s_barrier();
        __builtin_amdgcn_sched_barrier(0);
        if (kt < NT - 2) {
            STAGE4(cur);                       // tile kt+2 into the just-freed buffer
            __builtin_amdgcn_sched_barrier(0); // keep issue point ahead of MFMA tail
        }

        __builtin_amdgcn_s_setprio(1);
#pragma unroll
        for (int mi = 4; mi < 8; ++mi)
#pragma unroll
            for (int ni = 0; ni < 4; ++ni)
                acc[mi][ni] = __builtin_amdgcn_mfma_f32_16x16x32_f16(a[mi], b[ni], acc[mi][ni], 0, 0, 0);
        __builtin_amdgcn_s_setprio(0);

        // counted wait: oldest 4 = tile kt+1 (next buffer); tile kt+2 stays in flight
        if (kt < NT - 2)       asm volatile("s_waitcnt vmcnt(4)" ::: "memory");
        else if (kt == NT - 2) asm volatile("s_waitcnt vmcnt(0)" ::: "memory");
        if (kt < NT - 1) __builtin_amdgcn_s_barrier();
        cur ^= 1;
    }
#undef STAGE4

    // C/D layout: col = lane&15, row = quad*4 + reg  [m89/m91 verified]
    if (mode == 0) {
        u16* out = (u16*)outv;                       // [B, NH, S, HD]
#pragma unroll
        for (int mi = 0; mi < 8; ++mi)
#pragma unroll
            for (int r = 0; r < 4; ++r) {
                int m  = by*256 + wm*128 + mi*16 + quad*4 + r;
                int bb = m >> 8, ss = m & 255;
#pragma unroll
                for (int ni = 0; ni < 4; ++ni) {
                    int n = bx*256 + wn*64 + ni*16 + r15;
                    int h = n >> 7, d = n & 127;
                    out[(((size_t)(bb*NH_ + h)) * S_ + ss) * HD_ + d] = f2h(acc[mi][ni][r]);
                }
            }
    } else {
        float* out = (float*)outv;                   // [M, 2048]
#pragma unroll
        for (int mi = 0; mi < 8; ++mi)
#pragma unroll
            for (int r = 0; r < 4; ++r) {
                int m = by*256 + wm*128 + mi*16 + quad*4 + r;
                size_t base = (size_t)m * H_ + bx*256 + wn*64 + r15;
#pragma unroll
                for (int ni = 0; ni < 4; ++ni)
                    out[base + ni*16] = acc[mi][ni][r];
            }
    }
}

// ---------------------------------------------------------------------------
// RoPE in-place on fp16 q,k in [B,NH,S,HD]; pair (i, i+64). Accurate cosf/sinf.
// ---------------------------------------------------------------------------
__global__ __launch_bounds__(256) void rope_f16(u16* __restrict__ q, u16* __restrict__ k)
{
    int idx = blockIdx.x * 256 + threadIdx.x;       // pair index
    u16* p = blockIdx.y ? k : q;
    int i  = idx & 63;
    int s  = (idx >> 6) & (S_ - 1);
    int bh = idx >> 14;
    size_t base = ((size_t)bh * S_ + s) * HD_;
    float f = expf((float)i * -0.14391156831212788f);   // 10000^(-i/64)
    float ang = (float)s * f;
    float c = cosf(ang), sn = sinf(ang);
    float x0 = h2f(p[base + i]), x1 = h2f(p[base + i + 64]);
    p[base + i]      = f2h(x0 * c - x1 * sn);
    p[base + i + 64] = f2h(x1 * c + x0 * sn);
}

// ---------------------------------------------------------------------------
// Attention, fp16 MFMA. Block = 256 thr (4 waves) handles (b,h) x 64 q-rows.
// Scores kept in C-layout registers (wave w owns q-rows w*16..+15, all 256 cols);
// softmax via 16-lane shuffle; P -> LDS (plane-major) -> A-operand for PV.
// LDS 48KB: shQK = Qs(16K)+Ks(16K) reused as Pb(32K); shV = Vt transposed (16K).
// Output written as single fp16 [M, 2048] for the final fp16 GEMM.
// ---------------------------------------------------------------------------
#define SCALE 0.08838834764831845f

__global__ __launch_bounds__(256) void attn_mfma(
    const u16* __restrict__ Q, const u16* __restrict__ K, const u16* __restrict__ V,
    u16* __restrict__ O)
{
    __shared__ u16 shQK[16384];
    __shared__ u16 shV[8192];
    u16* Qs = shQK;            // planes [16][64] chunks of 8 fp16
    u16* Ks = shQK + 8192;     // planes [16][64]
    u16* Pb = shQK;            // planes [32][64]  (after Qs/Ks dead)

    const int tid = threadIdx.x;
    const int lane = tid & 63, w = tid >> 6;
    const int r15 = lane & 15, quad = lane >> 4;
    const int bh = blockIdx.x;
    const int q0 = blockIdx.y << 6;
    const int wq = w * 16;

    const u16* Qg = Q + ((size_t)bh * S_ + q0) * HD_;
    const u16* Kg = K + (size_t)bh * S_ * HD_;
    const u16* Vg = V + (size_t)bh * S_ * HD_;

    // stage Q tile 64x128 -> plane-major
#pragma unroll
    for (int p = 0; p < 4; ++p) {
        int task = tid + (p << 8);
        int r = task & 63, c = task >> 6;
        *(uint4*)&Qs[(c*64 + r)*8] = *(const uint4*)&Qg[(size_t)r*HD_ + c*8];
    }

    const floatx4 fzero = {0.f, 0.f, 0.f, 0.f};
    floatx4 sc[4][4];                          // [kt][ni]; rows wq+quad*4+reg
    for (int kt = 0; kt < 4; ++kt) {
        __syncthreads();
#pragma unroll
        for (int p = 0; p < 4; ++p) {
            int task = tid + (p << 8);
            int r = task & 63, c = task >> 6;
            *(uint4*)&Ks[(c*64 + r)*8] = *(const uint4*)&Kg[(size_t)(kt*64 + r)*HD_ + c*8];
        }
        __syncthreads();
#pragma unroll
        for (int ni = 0; ni < 4; ++ni) sc[kt][ni] = fzero;
#pragma unroll
        for (int ks = 0; ks < 4; ++ks) {
            half8 a = *(const half8*)&Qs[((ks*4 + quad)*64 + wq + r15)*8];
#pragma unroll
            for (int ni = 0; ni < 4; ++ni) {
                half8 b = *(const half8*)&Ks[((ks*4 + quad)*64 + ni*16 + r15)*8];
                sc[kt][ni] = __builtin_amdgcn_mfma_f32_16x16x32_f16(a, b, sc[kt][ni], 0, 0, 0);
            }
        }
    }
    __syncthreads();   // all Qs/Ks reads complete before Pb overwrites them

    // ---- softmax in registers (rows wq+quad*4+r; 16 col-lanes via shuffle) ----
#pragma unroll
    for (int kt = 0; kt < 4; ++kt)
#pragma unroll
        for (int ni = 0; ni < 4; ++ni) sc[kt][ni] *= SCALE;

    float rinv4[4], mrow4[4];
#pragma unroll
    for (int r = 0; r < 4; ++r) {
        float m = -1e30f;
#pragma unroll
        for (int kt = 0; kt < 4; ++kt)
#pragma unroll
            for (int ni = 0; ni < 4; ++ni) m = fmaxf(m, sc[kt][ni][r]);
#pragma unroll
        for (int o = 1; o < 16; o <<= 1) m = fmaxf(m, __shfl_xor(m, o));
        mrow4[r] = m;
    }
#pragma unroll
    for (int r = 0; r < 4; ++r) {
        float ssum = 0.f;
#pragma unroll
        for (int kt = 0; kt < 4; ++kt)
#pragma unroll
            for (int ni = 0; ni < 4; ++ni) {
                float e = __expf(sc[kt][ni][r] - mrow4[r]);
                sc[kt][ni][r] = e;
                ssum += e;
            }
#pragma unroll
        for (int o = 1; o < 16; o <<= 1) ssum += __shfl_xor(ssum, o);
        rinv4[r] = 1.f / ssum;
    }
    // write P fp16 -> Pb plane-major: elem(row,col) at chunk (col>>3)*64+row
#pragma unroll
    for (int r = 0; r < 4; ++r) {
        int row = wq + quad*4 + r;
#pragma unroll
        for (int kt = 0; kt < 4; ++kt)
#pragma unroll
            for (int ni = 0; ni < 4; ++ni) {
                int col = kt*64 + ni*16 + r15;
                Pb[((col >> 3)*64 + row)*8 + (col & 7)] = f2h(sc[kt][ni][r] * rinv4[r]);
            }
    }

    // ---- O = P V ----
    floatx4 oacc[8];
#pragma unroll
    for (int di = 0; di < 8; ++di) oacc[di] = fzero;

    for (int vt = 0; vt < 4; ++vt) {
        __syncthreads();
        // stage V tile transposed: Vt planes [8][128] chunks; elem(d,s') at chunk (s'>>3)*128+d
#pragma unroll
        for (int p = 0; p < 4; ++p) {
            int task = tid + (p << 8);
            int r = task & 63, dc = task >> 6;          // s' = r, d-chunk dc
            ushort8 v = *(const ushort8*)&Vg[(size_t)(vt*64 + r)*HD_ + dc*8];
#pragma unroll
            for (int j = 0; j < 8; ++j)
                shV[(((r >> 3)*128) + dc*8 + j)*8 + (r & 7)] = v[j];
        }
        __syncthreads();
#pragma unroll
        for (int ks = 0; ks < 2; ++ks) {
            int colbase = vt*64 + ks*32 + quad*8;
            half8 a = *(const half8*)&Pb[((colbase >> 3)*64 + wq + r15)*8];
            int sp = ks*32 + quad*8;
#pragma unroll
            for (int di = 0; di < 8; ++di) {
                half8 b = *(const half8*)&shV[((sp >> 3)*128 + di*16 + r15)*8];
                oacc[di] = __builtin_amdgcn_mfma_f32_16x16x32_f16(a, b, oacc[di], 0, 0, 0);
            }
        }
    }

    // epilogue: att[m][n] -> fp16, m = b*256+s, n = h*128 + d
    const int brow = bh >> 4, h = bh & 15;
#pragma unroll
    for (int r = 0; r < 4; ++r) {
        size_t base = ((size_t)(brow*S_ + q0 + wq + quad*4 + r)) * H_ + h*128 + r15;
#pragma unroll
        for (int di = 0; di < 8; ++di)
            O[base + di*16] = f2h(oacc[di][r]);
    }
}

// ---------------------------------------------------------------------------
extern "C" void kernel_launch(void* const* d_in, const int* in_sizes, int n_in,
                              void* d_out, int out_size, void* d_ws, size_t ws_size,
                              hipStream_t stream)
{
    const float* X  = (const float*)d_in[0];
    const float* Wp[4] = {(const float*)d_in[1], (const float*)d_in[2],
                          (const float*)d_in[3], (const float*)d_in[4]};   // q,k,v,o
    float* outp = (float*)d_out;

    char* ws = (char*)d_ws;
    u16* Xh  = (u16*)ws;                          //  33.5 MB [M,2048] fp16
    u16* W16 = (u16*)(ws + 33554432);             //  4 x 8.39 MB fp16
    u16* Qh  = (u16*)(ws + 67108864);             //  33.5 MB [B,NH,S,HD]
    u16* Kh  = (u16*)(ws + 100663296);
    u16* Vh  = (u16*)(ws + 134217728);            //  total 168 MB
    u16* Ah  = Xh;                                // alias: X dead after projections

    cvt16<<<(M_*H_/4)/256, 256, 0, stream>>>(X, Xh, M_*H_/4);
    for (int i = 0; i < 4; ++i)
        cvt16<<<(H_*H_/4)/256, 256, 0, stream>>>(Wp[i], W16 + (size_t)i*4194304, H_*H_/4);

    gemm_f16<<<256, 512, 0, stream>>>(Xh, W16 + 0*4194304, Qh, 0);
    gemm_f16<<<256, 512, 0, stream>>>(Xh, W16 + 1*4194304, Kh, 0);
    gemm_f16<<<256, 512, 0, stream>>>(Xh, W16 + 2*4194304, Vh, 0);
    rope_f16<<<dim3(32768, 2), 256, 0, stream>>>(Qh, Kh);
    attn_mfma<<<dim3(B_*NH_, 4), 256, 0, stream>>>(Qh, Kh, Vh, Ah);
    gemm_f16<<<256, 512, 0, stream>>>(Ah, W16 + 3*4194304, outp, 1);
}

// Round 6
// 641.834 us; speedup vs baseline: 2.0394x; 1.1353x over previous
//
#include <hip/hip_runtime.h>
#include <math.h>

#define B_ 32
#define S_ 256
#define H_ 2048
#define NH_ 16
#define HD_ 128
#define M_ (B_*S_)
#define K_ H_

typedef unsigned short u16;
typedef unsigned int   u32;
typedef _Float16 half8 __attribute__((ext_vector_type(8)));   // 8 fp16 (4 VGPRs) MFMA A/B frag
typedef __attribute__((ext_vector_type(8))) unsigned short ushort8;
typedef __attribute__((ext_vector_type(4))) float  floatx4;   // MFMA C/D frag

typedef __attribute__((address_space(3))) u32 lds_u32;
typedef __attribute__((address_space(1))) const u32 glb_u32;

__device__ __forceinline__ u16 f2h(float f) {
    _Float16 h = (_Float16)f;          // v_cvt_f16_f32, RNE
    u16 r; __builtin_memcpy(&r, &h, 2); return r;
}
__device__ __forceinline__ float h2f(u16 u) {
    _Float16 h; __builtin_memcpy(&h, &u, 2); return (float)h;
}
// async 16B global->LDS; lds addr must be wave-uniform base (+ lane*16 implicit)
__device__ __forceinline__ void gll16(const u16* g, u16* l) {
    __builtin_amdgcn_global_load_lds((glb_u32*)g, (lds_u32*)l, 16, 0, 0);
}

// ---------------------------------------------------------------------------
// fp32 -> fp16 (RNE)
// ---------------------------------------------------------------------------
__global__ __launch_bounds__(256) void cvt16(const float* __restrict__ x,
    u16* __restrict__ o, int n4)
{
    int i = blockIdx.x * 256 + threadIdx.x;
    if (i >= n4) return;
    float4 v = ((const float4*)x)[i];
    ((ushort4*)o)[i] = make_ushort4(f2h(v.x), f2h(v.y), f2h(v.z), f2h(v.w));
}

// ---------------------------------------------------------------------------
// C = A @ B^T, single-pass fp16 MFMA, fp32 acc.
// 256x256 tile, BK=32, 512 thr = 8 waves (2Mx4N), wave tile 128x64.
// m201-faithful 4-phase schedule: per phase {small ds_read bundle (B first!);
// 1 gll16 staging piece; sched_barrier; s_barrier; sched_barrier; setprio(1);
// 8-MFMA cluster; setprio(0)}.  Waves start MFMA staggered by LDS-queue
// position; phase i+1 reads drain under phase i MFMA.  TRIPLE buffer (96 KiB:
// 2 streams x 3 bufs x 16 KiB): tile kt+2's buffer (held tile kt-1, dead since
// end of step kt-1) is free from step start -> staging spreads across phases
// instead of clumping after an all-reads-drained rendezvous.  Counted
// vmcnt(4) once per step: tile kt+1 landed, kt+2 stays in flight; never
// drains to 0 in the main loop.
// LDS plane-major: chunk (row,kc) at slot kc*256+row -> conflict-free b128
// frag reads + gll16-linear staging.  T1: bijective XCD swizzle.
// mode 0: fused QKV, N=6144, fp16 out, n>>11 selects Q/K/V plane (contiguous,
//         16777216 u16 apart), head-major [B,NH,S,HD].
// mode 1: fp32 [M,2048].
// ---------------------------------------------------------------------------
__global__ __launch_bounds__(512, 2) void gemm_f16(
    const u16* __restrict__ A, const u16* __restrict__ Bm,
    void* __restrict__ outv, int mode, int nbx)
{
    __shared__ u16 sA[3][8192], sB[3][8192];   // 96 KiB

    const int tid  = threadIdx.x;
    const int lane = tid & 63, w = tid >> 6;
    const int wm   = w >> 2, wn = w & 3;            // wave grid 2 (M) x 4 (N)
    const int r15  = lane & 15, quad = lane >> 4;

    // T1: bijective XCD swizzle. nwg = 32*nbx (768 or 256), chunk = 4*nbx/XCD
    const int bid = blockIdx.x;
    const int swz = (bid & 7) * (nbx << 2) + (bid >> 3);
    const int by  = swz / nbx;                       // M-tile 0..31 (A-panel)
    const int bx  = swz - by * nbx;                  // N-tile 0..nbx-1

    // staging: thread -> (row = tid&255, chunks c0 and c0+2), c0 = tid>>8
    const int srow = tid & 255;
    const int c0   = tid >> 8;
    const u16* gA = A  + (size_t)(by*256 + srow) * K_ + c0*8;
    const u16* gB = Bm + (size_t)(bx*256 + srow) * K_ + c0*8;
    // per-wave LDS segments (u16 units)
    const int segE = w * 512;
    const int segO = 4096 + w * 512;

    // fragment read bases (u16 index): chunk (row,kc) at slot kc*256+row
    const int aBase = (quad*256 + wm*128 + r15) * 8;
    const int bBase = (quad*256 + wn*64  + r15) * 8;

    const floatx4 fzero = {0.f, 0.f, 0.f, 0.f};
    floatx4 acc[8][4];
#pragma unroll
    for (int mi = 0; mi < 8; ++mi)
#pragma unroll
        for (int ni = 0; ni < 4; ++ni) acc[mi][ni] = fzero;

#define MFMA_(d, x, y) d = __builtin_amdgcn_mfma_f32_16x16x32_f16(x, y, d, 0, 0, 0)
#define PHASE_BAR() do { __builtin_amdgcn_sched_barrier(0); \
        __builtin_amdgcn_s_barrier(); \
        __builtin_amdgcn_sched_barrier(0); } while (0)

    // prologue: stage tiles 0 (buf0) and 1 (buf1); wait for tile 0 only
    gll16(gA,      &sA[0][segE]); gll16(gA + 16, &sA[0][segO]);
    gll16(gB,      &sB[0][segE]); gll16(gB + 16, &sB[0][segO]);
    gA += 32; gB += 32;
    gll16(gA,      &sA[1][segE]); gll16(gA + 16, &sA[1][segO]);
    gll16(gB,      &sB[1][segE]); gll16(gB + 16, &sB[1][segO]);
    gA += 32; gB += 32;
    asm volatile("s_waitcnt vmcnt(4)" ::: "memory");
    __builtin_amdgcn_s_barrier();

    const int NT = K_/32;
    int b0 = 0, b1 = 1, b2 = 2;
    for (int kt = 0; kt < NT; ++kt) {
        const u16* pA = sA[b0]; const u16* pB = sB[b0];
        u16* tA = sA[b2];       u16* tB = sB[b2];
        const bool st = (kt < NT - 2);
        half8 a[8], b[4];

        // ---- P0: B frags (needed by every cluster -> first) + A rows 0,1 ----
#pragma unroll
        for (int ni = 0; ni < 4; ++ni) b[ni] = *(const half8*)&pB[bBase + ni*128];
        a[0] = *(const half8*)&pA[aBase + 0*128];
        a[1] = *(const half8*)&pA[aBase + 1*128];
        if (st) gll16(gA, &tA[segE]);
        PHASE_BAR();
        __builtin_amdgcn_s_setprio(1);
#pragma unroll
        for (int ni = 0; ni < 4; ++ni) { MFMA_(acc[0][ni], a[0], b[ni]); MFMA_(acc[1][ni], a[1], b[ni]); }
        __builtin_amdgcn_s_setprio(0);

        // ---- P1: A rows 2,3 ----
        a[2] = *(const half8*)&pA[aBase + 2*128];
        a[3] = *(const half8*)&pA[aBase + 3*128];
        if (st) gll16(gA + 16, &tA[segO]);
        PHASE_BAR();
        __builtin_amdgcn_s_setprio(1);
#pragma unroll
        for (int ni = 0; ni < 4; ++ni) { MFMA_(acc[2][ni], a[2], b[ni]); MFMA_(acc[3][ni], a[3], b[ni]); }
        __builtin_amdgcn_s_setprio(0);

        // ---- P2: A rows 4,5 ----
        a[4] = *(const half8*)&pA[aBase + 4*128];
        a[5] = *(const half8*)&pA[aBase + 5*128];
        if (st) gll16(gB, &tB[segE]);
        PHASE_BAR();
        __builtin_amdgcn_s_setprio(1);
#pragma unroll
        for (int ni = 0; ni < 4; ++ni) { MFMA_(acc[4][ni], a[4], b[ni]); MFMA_(acc[5][ni], a[5], b[ni]); }
        __builtin_amdgcn_s_setprio(0);

        // ---- P3: A rows 6,7 ----
        a[6] = *(const half8*)&pA[aBase + 6*128];
        a[7] = *(const half8*)&pA[aBase + 7*128];
        if (st) gll16(gB + 16, &tB[segO]);
        PHASE_BAR();
        __builtin_amdgcn_s_setprio(1);
#pragma unroll
        for (int ni = 0; ni < 4; ++ni) { MFMA_(acc[6][ni], a[6], b[ni]); MFMA_(acc[7][ni], a[7], b[ni]); }
        __builtin_amdgcn_s_setprio(0);

        // ---- step end: counted wait; tile kt+1 landed, kt+2 in flight ----
        if (kt < NT - 2)       asm volatile("s_waitcnt vmcnt(4)" ::: "memory");
        else if (kt == NT - 2) asm volatile("s_waitcnt vmcnt(0)" ::: "memory");
        PHASE_BAR();
        gA += 32; gB += 32;
        int t = b0; b0 = b1; b1 = b2; b2 = t;
    }
#undef MFMA_
#undef PHASE_BAR

    // C/D layout: col = lane&15, row = quad*4 + reg  [m89/m91 verified]
    if (mode == 0) {
        u16* out = (u16*)outv;     // Q plane base; K,V contiguous 16777216 u16 apart
#pragma unroll
        for (int mi = 0; mi < 8; ++mi)
#pragma unroll
            for (int r = 0; r < 4; ++r) {
                int m  = by*256 + wm*128 + mi*16 + quad*4 + r;
                int bb = m >> 8, ss = m & 255;
#pragma unroll
                for (int ni = 0; ni < 4; ++ni) {
                    int n = bx*256 + wn*64 + ni*16 + r15;
                    int which = n >> 11, rem = n & 2047;
                    int h = rem >> 7, d = rem & 127;
                    out[(size_t)which*16777216 +
                        (((size_t)(bb*NH_ + h)) * S_ + ss) * HD_ + d] = f2h(acc[mi][ni][r]);
                }
            }
    } else {
        float* out = (float*)outv;                   // [M, 2048]
#pragma unroll
        for (int mi = 0; mi < 8; ++mi)
#pragma unroll
            for (int r = 0; r < 4; ++r) {
                int m = by*256 + wm*128 + mi*16 + quad*4 + r;
                size_t base = (size_t)m * H_ + bx*256 + wn*64 + r15;
#pragma unroll
                for (int ni = 0; ni < 4; ++ni)
                    out[base + ni*16] = acc[mi][ni][r];
            }
    }
}

// ---------------------------------------------------------------------------
// RoPE in-place on fp16 q,k in [B,NH,S,HD]; pair (i, i+64). Accurate cosf/sinf.
// ---------------------------------------------------------------------------
__global__ __launch_bounds__(256) void rope_f16(u16* __restrict__ q, u16* __restrict__ k)
{
    int idx = blockIdx.x * 256 + threadIdx.x;       // pair index
    u16* p = blockIdx.y ? k : q;
    int i  = idx & 63;
    int s  = (idx >> 6) & (S_ - 1);
    int bh = idx >> 14;
    size_t base = ((size_t)bh * S_ + s) * HD_;
    float f = expf((float)i * -0.14391156831212788f);   // 10000^(-i/64)
    float ang = (float)s * f;
    float c = cosf(ang), sn = sinf(ang);
    float x0 = h2f(p[base + i]), x1 = h2f(p[base + i + 64]);
    p[base + i]      = f2h(x0 * c - x1 * sn);
    p[base + i + 64] = f2h(x1 * c + x0 * sn);
}

// ---------------------------------------------------------------------------
// Attention, fp16 MFMA. Block = 256 thr (4 waves) handles (b,h) x 64 q-rows.
// Scores kept in C-layout registers; softmax via 16-lane shuffle; P -> LDS
// (plane-major) -> A-operand for PV.  Output: single fp16 [M, 2048].
// ---------------------------------------------------------------------------
#define SCALE 0.08838834764831845f

__global__ __launch_bounds__(256) void attn_mfma(
    const u16* __restrict__ Q, const u16* __restrict__ K, const u16* __restrict__ V,
    u16* __restrict__ O)
{
    __shared__ u16 shQK[16384];
    __shared__ u16 shV[8192];
    u16* Qs = shQK;            // planes [16][64] chunks of 8 fp16
    u16* Ks = shQK + 8192;     // planes [16][64]
    u16* Pb = shQK;            // planes [32][64]  (after Qs/Ks dead)

    const int tid = threadIdx.x;
    const int lane = tid & 63, w = tid >> 6;
    const int r15 = lane & 15, quad = lane >> 4;
    const int bh = blockIdx.x;
    const int q0 = blockIdx.y << 6;
    const int wq = w * 16;

    const u16* Qg = Q + ((size_t)bh * S_ + q0) * HD_;
    const u16* Kg = K + (size_t)bh * S_ * HD_;
    const u16* Vg = V + (size_t)bh * S_ * HD_;

    // stage Q tile 64x128 -> plane-major
#pragma unroll
    for (int p = 0; p < 4; ++p) {
        int task = tid + (p << 8);
        int r = task & 63, c = task >> 6;
        *(uint4*)&Qs[(c*64 + r)*8] = *(const uint4*)&Qg[(size_t)r*HD_ + c*8];
    }

    const floatx4 fzero = {0.f, 0.f, 0.f, 0.f};
    floatx4 sc[4][4];                          // [kt][ni]; rows wq+quad*4+reg
    for (int kt = 0; kt < 4; ++kt) {
        __syncthreads();
#pragma unroll
        for (int p = 0; p < 4; ++p) {
            int task = tid + (p << 8);
            int r = task & 63, c = task >> 6;
            *(uint4*)&Ks[(c*64 + r)*8] = *(const uint4*)&Kg[(size_t)(kt*64 + r)*HD_ + c*8];
        }
        __syncthreads();
#pragma unroll
        for (int ni = 0; ni < 4; ++ni) sc[kt][ni] = fzero;
#pragma unroll
        for (int ks = 0; ks < 4; ++ks) {
            half8 a = *(const half8*)&Qs[((ks*4 + quad)*64 + wq + r15)*8];
#pragma unroll
            for (int ni = 0; ni < 4; ++ni) {
                half8 b = *(const half8*)&Ks[((ks*4 + quad)*64 + ni*16 + r15)*8];
                sc[kt][ni] = __builtin_amdgcn_mfma_f32_16x16x32_f16(a, b, sc[kt][ni], 0, 0, 0);
            }
        }
    }
    __syncthreads();   // all Qs/Ks reads complete before Pb overwrites them

    // ---- softmax in registers (rows wq+quad*4+r; 16 col-lanes via shuffle) ----
#pragma unroll
    for (int kt = 0; kt < 4; ++kt)
#pragma unroll
        for (int ni = 0; ni < 4; ++ni) sc[kt][ni] *= SCALE;

    float rinv4[4], mrow4[4];
#pragma unroll
    for (int r = 0; r < 4; ++r) {
        float m = -1e30f;
#pragma unroll
        for (int kt = 0; kt < 4; ++kt)
#pragma unroll
            for (int ni = 0; ni < 4; ++ni) m = fmaxf(m, sc[kt][ni][r]);
#pragma unroll
        for (int o = 1; o < 16; o <<= 1) m = fmaxf(m, __shfl_xor(m, o));
        mrow4[r] = m;
    }
#pragma unroll
    for (int r = 0; r < 4; ++r) {
        float ssum = 0.f;
#pragma unroll
        for (int kt = 0; kt < 4; ++kt)
#pragma unroll
            for (int ni = 0; ni < 4; ++ni) {
                float e = __expf(sc[kt][ni][r] - mrow4[r]);
                sc[kt][ni][r] = e;
                ssum += e;
            }
#pragma unroll
        for (int o = 1; o < 16; o <<= 1) ssum += __shfl_xor(ssum, o);
        rinv4[r] = 1.f / ssum;
    }
    // write P fp16 -> Pb plane-major: elem(row,col) at chunk (col>>3)*64+row
#pragma unroll
    for (int r = 0; r < 4; ++r) {
        int row = wq + quad*4 + r;
#pragma unroll
        for (int kt = 0; kt < 4; ++kt)
#pragma unroll
            for (int ni = 0; ni < 4; ++ni) {
                int col = kt*64 + ni*16 + r15;
                Pb[((col >> 3)*64 + row)*8 + (col & 7)] = f2h(sc[kt][ni][r] * rinv4[r]);
            }
    }

    // ---- O = P V ----
    floatx4 oacc[8];
#pragma unroll
    for (int di = 0; di < 8; ++di) oacc[di] = fzero;

    for (int vt = 0; vt < 4; ++vt) {
        __syncthreads();
        // stage V tile transposed: Vt planes [8][128] chunks; elem(d,s') at chunk (s'>>3)*128+d
#pragma unroll
        for (int p = 0; p < 4; ++p) {
            int task = tid + (p << 8);
            int r = task & 63, dc = task >> 6;          // s' = r, d-chunk dc
            ushort8 v = *(const ushort8*)&Vg[(size_t)(vt*64 + r)*HD_ + dc*8];
#pragma unroll
            for (int j = 0; j < 8; ++j)
                shV[(((r >> 3)*128) + dc*8 + j)*8 + (r & 7)] = v[j];
        }
        __syncthreads();
#pragma unroll
        for (int ks = 0; ks < 2; ++ks) {
            int colbase = vt*64 + ks*32 + quad*8;
            half8 a = *(const half8*)&Pb[((colbase >> 3)*64 + wq + r15)*8];
            int sp = ks*32 + quad*8;
#pragma unroll
            for (int di = 0; di < 8; ++di) {
                half8 b = *(const half8*)&shV[((sp >> 3)*128 + di*16 + r15)*8];
                oacc[di] = __builtin_amdgcn_mfma_f32_16x16x32_f16(a, b, oacc[di], 0, 0, 0);
            }
        }
    }

    // epilogue: att[m][n] -> fp16, m = b*256+s, n = h*128 + d
    const int brow = bh >> 4, h = bh & 15;
#pragma unroll
    for (int r = 0; r < 4; ++r) {
        size_t base = ((size_t)(brow*S_ + q0 + wq + quad*4 + r)) * H_ + h*128 + r15;
#pragma unroll
        for (int di = 0; di < 8; ++di)
            O[base + di*16] = f2h(oacc[di][r]);
    }
}

// ---------------------------------------------------------------------------
extern "C" void kernel_launch(void* const* d_in, const int* in_sizes, int n_in,
                              void* d_out, int out_size, void* d_ws, size_t ws_size,
                              hipStream_t stream)
{
    const float* X  = (const float*)d_in[0];
    const float* Wp[4] = {(const float*)d_in[1], (const float*)d_in[2],
                          (const float*)d_in[3], (const float*)d_in[4]};   // q,k,v,o
    float* outp = (float*)d_out;

    char* ws = (char*)d_ws;
    u16* Xh  = (u16*)ws;                          //  33.5 MB [M,2048] fp16
    u16* W16 = (u16*)(ws + 33554432);             //  4 x 8.39 MB fp16 (q,k,v,o stacked)
    u16* Qh  = (u16*)(ws + 67108864);             //  33.5 MB [B,NH,S,HD]
    u16* Kh  = (u16*)(ws + 100663296);            //  (Q,K,V contiguous!)
    u16* Vh  = (u16*)(ws + 134217728);            //  total 168 MB
    u16* Ah  = Xh;                                // alias: X dead after projections

    cvt16<<<(M_*H_/4)/256, 256, 0, stream>>>(X, Xh, M_*H_/4);
    for (int i = 0; i < 4; ++i)
        cvt16<<<(H_*H_/4)/256, 256, 0, stream>>>(Wp[i], W16 + (size_t)i*4194304, H_*H_/4);

    // fused QKV projection: B = [Wq;Wk;Wv] (contiguous), N = 6144, grid 768
    gemm_f16<<<768, 512, 0, stream>>>(Xh, W16, Qh, 0, 24);
    rope_f16<<<dim3(32768, 2), 256, 0, stream>>>(Qh, Kh);
    attn_mfma<<<dim3(B_*NH_, 4), 256, 0, stream>>>(Qh, Kh, Vh, Ah);
    gemm_f16<<<256, 512, 0, stream>>>(Ah, W16 + 3*4194304, outp, 1, 8);
}